// Round 1
// baseline (747.379 us; speedup 1.0000x reference)
//
#include <hip/hip_runtime.h>
#include <hip/hip_cooperative_groups.h>
#include <math.h>

namespace cg = cooperative_groups;

#define H 1024
#define S 32768
#define GRID 2048
#define TPB 256

// ---------------------------------------------------------------------------
// Fused cooperative kernel: matvec -> reduce -> energies -> softmax -> out
// Grid = 2048 blocks x 256 threads = 8 blocks/CU x 256 CU (exactly resident).
// __launch_bounds__(256,8): 8 waves/SIMD -> <=64 VGPR, guarantees coop launch.
// Each wave owns 4 rows; their energies stay in REGISTERS across grid.sync()
// (no energies[] global round-trip).
// ---------------------------------------------------------------------------
extern "C" __global__ void __launch_bounds__(TPB, 8)
attn_fused_kernel(const float* __restrict__ W,
                  const float* __restrict__ hidden,
                  const float* __restrict__ enc,
                  float* __restrict__ vpart,   // [256][H]
                  float* __restrict__ v,       // [H]
                  float* __restrict__ mpart,   // [GRID]
                  float* __restrict__ spart,   // [GRID]
                  float* __restrict__ out)     // [S]
{
    cg::grid_group grid = cg::this_grid();
    const int t    = threadIdx.x;
    const int b    = blockIdx.x;
    const int wave = t >> 6;
    const int lane = t & 63;
    const int s0   = (b * 4 + wave) * 4;   // this wave's 4 rows

    __shared__ float lm[4], ls[4];
    __shared__ float rm[4], rs[4];

    // ---- Phase A: vpart[b][h] = sum_{o in [4b,4b+4)} W[o][h]*hidden[o]
    // 256 blocks active, float4 coalesced over columns.
    if (b < 256) {
        const int h4 = t * 4;
        const int o0 = b * 4;
        float4 acc = make_float4(0.f, 0.f, 0.f, 0.f);
#pragma unroll
        for (int i = 0; i < 4; ++i) {
            const float  hv = hidden[o0 + i];
            const float4 w  = *reinterpret_cast<const float4*>(&W[(size_t)(o0 + i) * H + h4]);
            acc.x += hv * w.x; acc.y += hv * w.y;
            acc.z += hv * w.z; acc.w += hv * w.w;
        }
        *reinterpret_cast<float4*>(&vpart[(size_t)b * H + h4]) = acc;
    }
    grid.sync();

    // ---- Phase B: v[c] = sum_p vpart[p][c]  (8 blocks x 128 threads)
    if (b < 8 && t < 128) {
        const int c = b * 128 + t;
        float acc = 0.f;
#pragma unroll 16
        for (int p = 0; p < 256; ++p)
            acc += vpart[(size_t)p * H + c];
        v[c] = acc;
    }
    grid.sync();

    // ---- Phase C: energies for this wave's 4 rows (kept in registers) +
    //      per-block online-softmax partial (m,s).
    float4 vv[4];
#pragma unroll
    for (int j = 0; j < 4; ++j)
        vv[j] = *reinterpret_cast<const float4*>(&v[j * 256 + lane * 4]);

    float e[4];
#pragma unroll
    for (int r = 0; r < 4; ++r) {
        const float* row = enc + (size_t)(s0 + r) * H;
        float acc = 0.f;
#pragma unroll
        for (int j = 0; j < 4; ++j) {
            const float4 ev = *reinterpret_cast<const float4*>(&row[j * 256 + lane * 4]);
            acc += ev.x * vv[j].x + ev.y * vv[j].y + ev.z * vv[j].z + ev.w * vv[j].w;
        }
        // butterfly: every lane ends with the full row sum
#pragma unroll
        for (int off = 32; off > 0; off >>= 1)
            acc += __shfl_xor(acc, off, 64);
        e[r] = acc;
    }

    const float mw = fmaxf(fmaxf(e[0], e[1]), fmaxf(e[2], e[3]));
    const float sw = __expf(e[0] - mw) + __expf(e[1] - mw) +
                     __expf(e[2] - mw) + __expf(e[3] - mw);
    if (lane == 0) { lm[wave] = mw; ls[wave] = sw; }
    __syncthreads();
    if (t == 0) {
        const float m = fmaxf(fmaxf(lm[0], lm[1]), fmaxf(lm[2], lm[3]));
        const float s = ls[0] * __expf(lm[0] - m) + ls[1] * __expf(lm[1] - m) +
                        ls[2] * __expf(lm[2] - m) + ls[3] * __expf(lm[3] - m);
        mpart[b] = m; spart[b] = s;
    }
    grid.sync();

    // ---- Phase D: every block redundantly reduces the 2048 (m,s) partials
    //      (16 KB, L2/L3-resident), then writes its own 16 outputs.
    float m8[8], s8[8];
#pragma unroll
    for (int i = 0; i < 8; ++i) {
        m8[i] = mpart[t * 8 + i];
        s8[i] = spart[t * 8 + i];
    }
    float mt = m8[0];
#pragma unroll
    for (int i = 1; i < 8; ++i) mt = fmaxf(mt, m8[i]);
#pragma unroll
    for (int off = 32; off > 0; off >>= 1)
        mt = fmaxf(mt, __shfl_xor(mt, off, 64));
    if (lane == 0) rm[wave] = mt;
    __syncthreads();
    const float gm = fmaxf(fmaxf(rm[0], rm[1]), fmaxf(rm[2], rm[3]));

    float st = 0.f;
#pragma unroll
    for (int i = 0; i < 8; ++i) st += s8[i] * __expf(m8[i] - gm);
#pragma unroll
    for (int off = 32; off > 0; off >>= 1)
        st += __shfl_xor(st, off, 64);
    if (lane == 0) rs[wave] = st;
    __syncthreads();
    const float inv = 1.0f / (rs[0] + rs[1] + rs[2] + rs[3]);

    // all lanes hold identical e[0..3]; lane 0 writes the wave's 4 outputs
    if (lane == 0) {
        float4 o4;
        o4.x = __expf(e[0] - gm) * inv;
        o4.y = __expf(e[1] - gm) * inv;
        o4.z = __expf(e[2] - gm) * inv;
        o4.w = __expf(e[3] - gm) * inv;
        *reinterpret_cast<float4*>(&out[s0]) = o4;
    }
}

// ===========================================================================
// Fallback path (baseline 4-kernel pipeline) — used only if the cooperative
// launch is rejected (capture/occupancy). Guarantees baseline behavior.
// ===========================================================================
__global__ void matvec_partial_kernel(const float* __restrict__ W,
                                      const float* __restrict__ hidden,
                                      float* __restrict__ vpart) {
    const int t = threadIdx.x;
    const int b = blockIdx.x;
    const int h4 = t * 4;
    float4 acc = make_float4(0.f, 0.f, 0.f, 0.f);
    const int o0 = b * 16;
#pragma unroll
    for (int i = 0; i < 16; ++i) {
        const int o = o0 + i;
        const float hv = hidden[o];
        const float4 w = *reinterpret_cast<const float4*>(&W[(size_t)o * H + h4]);
        acc.x += hv * w.x; acc.y += hv * w.y;
        acc.z += hv * w.z; acc.w += hv * w.w;
    }
    *reinterpret_cast<float4*>(&vpart[(size_t)b * H + h4]) = acc;
}

__global__ void matvec_reduce_kernel(const float* __restrict__ vpart,
                                     float* __restrict__ v) {
    const int t = threadIdx.x;
    const int h4 = t * 4;
    float4 acc = make_float4(0.f, 0.f, 0.f, 0.f);
#pragma unroll 8
    for (int b = 0; b < 64; ++b) {
        const float4 p = *reinterpret_cast<const float4*>(&vpart[(size_t)b * H + h4]);
        acc.x += p.x; acc.y += p.y; acc.z += p.z; acc.w += p.w;
    }
    *reinterpret_cast<float4*>(&v[h4]) = acc;
}

__global__ void energies_kernel(const float* __restrict__ enc,
                                const float* __restrict__ v,
                                float* __restrict__ energies,
                                float* __restrict__ mpart,
                                float* __restrict__ spart) {
    const int wave = threadIdx.x >> 6;
    const int lane = threadIdx.x & 63;
    const int gwave = blockIdx.x * 4 + wave;
    const int s0 = gwave * 4;

    float4 vv[4];
#pragma unroll
    for (int j = 0; j < 4; ++j)
        vv[j] = *reinterpret_cast<const float4*>(&v[j * 256 + lane * 4]);

    float e[4];
#pragma unroll
    for (int r = 0; r < 4; ++r) {
        const float* row = enc + (size_t)(s0 + r) * H;
        float acc = 0.f;
#pragma unroll
        for (int j = 0; j < 4; ++j) {
            const float4 ev = *reinterpret_cast<const float4*>(&row[j * 256 + lane * 4]);
            acc += ev.x * vv[j].x + ev.y * vv[j].y + ev.z * vv[j].z + ev.w * vv[j].w;
        }
#pragma unroll
        for (int off = 32; off > 0; off >>= 1)
            acc += __shfl_xor(acc, off, 64);
        e[r] = acc;
    }

    if (lane == 0) {
        energies[s0 + 0] = e[0];
        energies[s0 + 1] = e[1];
        energies[s0 + 2] = e[2];
        energies[s0 + 3] = e[3];
    }

    const float mw = fmaxf(fmaxf(e[0], e[1]), fmaxf(e[2], e[3]));
    const float sw = __expf(e[0] - mw) + __expf(e[1] - mw) +
                     __expf(e[2] - mw) + __expf(e[3] - mw);

    __shared__ float lm[4], ls[4];
    if (lane == 0) { lm[wave] = mw; ls[wave] = sw; }
    __syncthreads();
    if (threadIdx.x == 0) {
        const float m = fmaxf(fmaxf(lm[0], lm[1]), fmaxf(lm[2], lm[3]));
        const float s = ls[0] * __expf(lm[0] - m) + ls[1] * __expf(lm[1] - m) +
                        ls[2] * __expf(lm[2] - m) + ls[3] * __expf(lm[3] - m);
        mpart[blockIdx.x] = m;
        spart[blockIdx.x] = s;
    }
}

__global__ void finalize_kernel(const float* __restrict__ energies,
                                const float* __restrict__ mpart,
                                const float* __restrict__ spart,
                                float* __restrict__ out) {
    __shared__ float red[16];
    __shared__ float gm_s, gs_s;
    const int t = threadIdx.x;
    const int lane = t & 63;
    const int wid = t >> 6;

    float m = fmaxf(mpart[t], mpart[t + 1024]);
#pragma unroll
    for (int off = 32; off > 0; off >>= 1)
        m = fmaxf(m, __shfl_xor(m, off, 64));
    if (lane == 0) red[wid] = m;
    __syncthreads();
    if (t == 0) {
        float mm = red[0];
#pragma unroll
        for (int i = 1; i < 16; ++i) mm = fmaxf(mm, red[i]);
        gm_s = mm;
    }
    __syncthreads();
    const float gm = gm_s;

    float s = spart[t] * __expf(mpart[t] - gm) +
              spart[t + 1024] * __expf(mpart[t + 1024] - gm);
#pragma unroll
    for (int off = 32; off > 0; off >>= 1)
        s += __shfl_xor(s, off, 64);
    __syncthreads();
    if (lane == 0) red[wid] = s;
    __syncthreads();
    if (t == 0) {
        float ss = 0.f;
#pragma unroll
        for (int i = 0; i < 16; ++i) ss += red[i];
        gs_s = ss;
    }
    __syncthreads();
    const float inv = 1.0f / gs_s;

#pragma unroll
    for (int k = 0; k < S / 1024; ++k)
        out[t + k * 1024] = __expf(energies[t + k * 1024] - gm) * inv;
}

// ---------------------------------------------------------------------------
// Launch
// ---------------------------------------------------------------------------
extern "C" void kernel_launch(void* const* d_in, const int* in_sizes, int n_in,
                              void* d_out, int out_size, void* d_ws, size_t ws_size,
                              hipStream_t stream) {
    const float* hidden = (const float*)d_in[0];   // [1024]
    const float* enc    = (const float*)d_in[1];   // [32768, 1024]
    const float* W      = (const float*)d_in[2];   // [1024, 1024]
    // d_in[3] = b: (b . hidden) is constant across s -> cancels in softmax.
    float* out = (float*)d_out;                    // [32768]

    // fused-kernel workspace layout
    float* vpart = (float*)d_ws;                   // 256*H
    float* v     = vpart + 256 * H;                // H
    float* mpart = v + H;                          // GRID
    float* spart = mpart + GRID;                   // GRID

    void* args[] = { (void*)&W, (void*)&hidden, (void*)&enc,
                     (void*)&vpart, (void*)&v, (void*)&mpart, (void*)&spart,
                     (void*)&out };

    hipError_t err = hipLaunchCooperativeKernel(
        reinterpret_cast<void*>(attn_fused_kernel),
        dim3(GRID), dim3(TPB), args, 0, stream);

    if (err != hipSuccess) {
        // fallback: proven 4-kernel baseline (its own ws layout, same base)
        float* fvpart    = (float*)d_ws;           // 64*H
        float* fv        = fvpart + 64 * H;        // H
        float* fenergies = fv + H;                 // S
        float* fmpart    = fenergies + S;          // 2048
        float* fspart    = fmpart + 2048;          // 2048
        matvec_partial_kernel<<<64, 256, 0, stream>>>(W, hidden, fvpart);
        matvec_reduce_kernel<<<1, 256, 0, stream>>>(fvpart, fv);
        energies_kernel<<<2048, 256, 0, stream>>>(enc, fv, fenergies, fmpart, fspart);
        finalize_kernel<<<1, 1024, 0, stream>>>(fenergies, fmpart, fspart, out);
    }
}

// Round 2
// 218.459 us; speedup vs baseline: 3.4211x; 3.4211x over previous
//
#include <hip/hip_runtime.h>
#include <math.h>

#define H 1024
#define S 32768

// ---------------------------------------------------------------------------
// Stage 1: partial matvec  vpart[b][h] = sum_{o in [4b,4b+4)} W[o,h]*hidden[o]
// 256 blocks x 256 threads -> W (4 MiB) read fully parallel across CUs.
// Thread t handles columns h = 4t..4t+3 (float4, coalesced).
// ---------------------------------------------------------------------------
__global__ void matvec_partial_kernel(const float* __restrict__ W,
                                      const float* __restrict__ hidden,
                                      float* __restrict__ vpart) {
    const int t = threadIdx.x;
    const int b = blockIdx.x;
    const int h4 = t * 4;
    const int o0 = b * 4;
    float4 acc = make_float4(0.f, 0.f, 0.f, 0.f);
#pragma unroll
    for (int i = 0; i < 4; ++i) {
        const float  hv = hidden[o0 + i];
        const float4 w  = *reinterpret_cast<const float4*>(&W[(size_t)(o0 + i) * H + h4]);
        acc.x += hv * w.x; acc.y += hv * w.y;
        acc.z += hv * w.z; acc.w += hv * w.w;
    }
    *reinterpret_cast<float4*>(&vpart[(size_t)b * H + h4]) = acc;
}

// ---------------------------------------------------------------------------
// Stage 2: reduce 256 partials -> v[1024].
// 4 blocks x 64 threads; each thread owns one float4 column group.
// 1 MB of L2-resident reads, abundant MLP (256 independent loads/thread).
// ---------------------------------------------------------------------------
__global__ void matvec_reduce_kernel(const float* __restrict__ vpart,
                                     float* __restrict__ v) {
    const int idx = blockIdx.x * 64 + threadIdx.x;   // 0..255
    const int h4 = idx * 4;
    float4 acc = make_float4(0.f, 0.f, 0.f, 0.f);
#pragma unroll 8
    for (int p = 0; p < 256; ++p) {
        const float4 q = *reinterpret_cast<const float4*>(&vpart[(size_t)p * H + h4]);
        acc.x += q.x; acc.y += q.y; acc.z += q.z; acc.w += q.w;
    }
    *reinterpret_cast<float4*>(&v[h4]) = acc;
}

// ---------------------------------------------------------------------------
// Stage 3: energies + per-block online-softmax partials.
// 2048 blocks x 256 threads = exactly 8 blocks/CU, full occupancy.
// Each wave computes 4 rows; v stripe kept in registers across rows.
// Wave reads are 64 lanes x 16B = 1 KiB contiguous per instruction.
// ---------------------------------------------------------------------------
__global__ void energies_kernel(const float* __restrict__ enc,
                                const float* __restrict__ v,
                                float* __restrict__ energies,
                                float* __restrict__ mpart,
                                float* __restrict__ spart) {
    const int wave = threadIdx.x >> 6;
    const int lane = threadIdx.x & 63;
    const int gwave = blockIdx.x * 4 + wave;   // 0..8191
    const int s0 = gwave * 4;                  // 4 rows per wave

    float4 vv[4];
#pragma unroll
    for (int j = 0; j < 4; ++j)
        vv[j] = *reinterpret_cast<const float4*>(&v[j * 256 + lane * 4]);

    float e[4];
#pragma unroll
    for (int r = 0; r < 4; ++r) {
        const float* row = enc + (size_t)(s0 + r) * H;
        float acc = 0.f;
#pragma unroll
        for (int j = 0; j < 4; ++j) {
            const float4 ev = *reinterpret_cast<const float4*>(&row[j * 256 + lane * 4]);
            acc += ev.x * vv[j].x + ev.y * vv[j].y + ev.z * vv[j].z + ev.w * vv[j].w;
        }
        // butterfly: every lane ends with the full row sum
#pragma unroll
        for (int off = 32; off > 0; off >>= 1)
            acc += __shfl_xor(acc, off, 64);
        e[r] = acc;
    }

    if (lane == 0) {
        energies[s0 + 0] = e[0];
        energies[s0 + 1] = e[1];
        energies[s0 + 2] = e[2];
        energies[s0 + 3] = e[3];
    }

    // per-wave online softmax partial
    const float mw = fmaxf(fmaxf(e[0], e[1]), fmaxf(e[2], e[3]));
    const float sw = __expf(e[0] - mw) + __expf(e[1] - mw) +
                     __expf(e[2] - mw) + __expf(e[3] - mw);

    __shared__ float lm[4], ls[4];
    if (lane == 0) { lm[wave] = mw; ls[wave] = sw; }
    __syncthreads();
    if (threadIdx.x == 0) {
        const float m = fmaxf(fmaxf(lm[0], lm[1]), fmaxf(lm[2], lm[3]));
        const float s = ls[0] * __expf(lm[0] - m) + ls[1] * __expf(lm[1] - m) +
                        ls[2] * __expf(lm[2] - m) + ls[3] * __expf(lm[3] - m);
        mpart[blockIdx.x] = m;
        spart[blockIdx.x] = s;
    }
}

// ---------------------------------------------------------------------------
// Stage 4: finalize, PARALLEL. 128 blocks x 256 threads.
// Every block redundantly reduces the 2048 (m,s) partials (16 KB, L2/L3-
// resident; redundancy is free) then writes its own 256 outputs.
// Replaces the old single-block (one-CU, latency-bound) finalize.
// ---------------------------------------------------------------------------
__global__ void finalize_kernel(const float* __restrict__ energies,
                                const float* __restrict__ mpart,
                                const float* __restrict__ spart,
                                float* __restrict__ out) {
    const int t = threadIdx.x;
    const int lane = t & 63;
    const int wave = t >> 6;
    __shared__ float rm[4], rs[4];

    // 8 (m,s) pairs per thread, float4 loads
    const float4 ma = *reinterpret_cast<const float4*>(&mpart[t * 8]);
    const float4 mb = *reinterpret_cast<const float4*>(&mpart[t * 8 + 4]);
    const float4 sa = *reinterpret_cast<const float4*>(&spart[t * 8]);
    const float4 sb = *reinterpret_cast<const float4*>(&spart[t * 8 + 4]);

    float mt = fmaxf(fmaxf(fmaxf(ma.x, ma.y), fmaxf(ma.z, ma.w)),
                     fmaxf(fmaxf(mb.x, mb.y), fmaxf(mb.z, mb.w)));
#pragma unroll
    for (int off = 32; off > 0; off >>= 1)
        mt = fmaxf(mt, __shfl_xor(mt, off, 64));
    if (lane == 0) rm[wave] = mt;
    __syncthreads();
    const float gm = fmaxf(fmaxf(rm[0], rm[1]), fmaxf(rm[2], rm[3]));

    float st = sa.x * __expf(ma.x - gm) + sa.y * __expf(ma.y - gm) +
               sa.z * __expf(ma.z - gm) + sa.w * __expf(ma.w - gm) +
               sb.x * __expf(mb.x - gm) + sb.y * __expf(mb.y - gm) +
               sb.z * __expf(mb.z - gm) + sb.w * __expf(mb.w - gm);
#pragma unroll
    for (int off = 32; off > 0; off >>= 1)
        st += __shfl_xor(st, off, 64);
    if (lane == 0) rs[wave] = st;
    __syncthreads();
    const float inv = 1.0f / (rs[0] + rs[1] + rs[2] + rs[3]);

    const int i = blockIdx.x * 256 + t;      // 128*256 = 32768 = S
    out[i] = __expf(energies[i] - gm) * inv;
}

// ---------------------------------------------------------------------------
// Launch: 4 dispatches; kernel boundaries are the (cheap) barriers.
// grid.sync() measured ~200 us/sync on this chip (round 1) - never again.
// ---------------------------------------------------------------------------
extern "C" void kernel_launch(void* const* d_in, const int* in_sizes, int n_in,
                              void* d_out, int out_size, void* d_ws, size_t ws_size,
                              hipStream_t stream) {
    const float* hidden = (const float*)d_in[0];   // [1024]
    const float* enc    = (const float*)d_in[1];   // [32768, 1024]
    const float* W      = (const float*)d_in[2];   // [1024, 1024]
    // d_in[3] = b: (b . hidden) is constant across s -> cancels in softmax.
    float* out = (float*)d_out;                    // [32768]

    float* vpart    = (float*)d_ws;        // 256*1024
    float* v        = vpart + 256 * H;     // 1024
    float* energies = v + H;               // 32768
    float* mpart    = energies + S;        // 2048
    float* spart    = mpart + 2048;        // 2048

    matvec_partial_kernel<<<256, 256, 0, stream>>>(W, hidden, vpart);
    matvec_reduce_kernel<<<4, 64, 0, stream>>>(vpart, v);
    energies_kernel<<<2048, 256, 0, stream>>>(enc, v, energies, mpart, spart);
    finalize_kernel<<<128, 256, 0, stream>>>(energies, mpart, spart, out);
}

// Round 3
// 206.557 us; speedup vs baseline: 3.6183x; 1.0576x over previous
//
#include <hip/hip_runtime.h>
#include <math.h>

#define H 1024
#define S 32768

// ---------------------------------------------------------------------------
// Stage 1 (fused matvec): v[h] = sum_o W[o,h] * hidden[o], ONE dispatch.
// 32 blocks x 256 threads. Block b owns columns [b*32, b*32+32).
// Thread t: col-group c = t&7 (float4), row class j = t>>3; rows o = j + 32k.
// Wave reads 8 rows x 128 B full L2 lines per instruction. Hidden staged in
// LDS. LDS tree-reduce over the 32 row-classes per column group.
// ---------------------------------------------------------------------------
__global__ void matvec_v_kernel(const float* __restrict__ W,
                                const float* __restrict__ hidden,
                                float* __restrict__ v) {
    __shared__ float sh[H];
    __shared__ float4 red[256];
    const int t = threadIdx.x;
    const int b = blockIdx.x;
    const int c = t & 7;        // float4 col-group within block slice
    const int j = t >> 3;       // row class 0..31

    // stage hidden: 256 threads x float4
    *reinterpret_cast<float4*>(&sh[t * 4]) =
        *reinterpret_cast<const float4*>(&hidden[t * 4]);
    __syncthreads();

    const int colbase = b * 32 + c * 4;
    float4 acc = make_float4(0.f, 0.f, 0.f, 0.f);
#pragma unroll 8
    for (int k = 0; k < 32; ++k) {
        const int o = j + 32 * k;
        const float hv = sh[o];
        const float4 w = *reinterpret_cast<const float4*>(&W[(size_t)o * H + colbase]);
        acc.x += hv * w.x; acc.y += hv * w.y;
        acc.z += hv * w.z; acc.w += hv * w.w;
    }
    red[t] = acc;
    __syncthreads();
    // reduce across row classes (stride-8 partners share the same col-group)
#pragma unroll
    for (int off = 128; off >= 8; off >>= 1) {
        if (t < off) {
            float4 a = red[t], bb = red[t + off];
            a.x += bb.x; a.y += bb.y; a.z += bb.z; a.w += bb.w;
            red[t] = a;
        }
        __syncthreads();
    }
    if (t < 8)
        *reinterpret_cast<float4*>(&v[b * 32 + t * 4]) = red[t];
}

// ---------------------------------------------------------------------------
// Stage 2: energies + per-block online-softmax partials.
// 2048 blocks x 256 threads. Each wave computes 4 rows (16 KiB).
// ALL 16 float4 loads hoisted ahead of the FMA/butterfly chain so the
// memory pipe stays saturated regardless of compiler scheduling.
// ---------------------------------------------------------------------------
__global__ void energies_kernel(const float* __restrict__ enc,
                                const float* __restrict__ v,
                                float* __restrict__ energies,
                                float* __restrict__ mpart,
                                float* __restrict__ spart) {
    const int wave = threadIdx.x >> 6;
    const int lane = threadIdx.x & 63;
    const int gwave = blockIdx.x * 4 + wave;   // 0..8191
    const int s0 = gwave * 4;                  // 4 rows per wave

    float4 vv[4];
#pragma unroll
    for (int j = 0; j < 4; ++j)
        vv[j] = *reinterpret_cast<const float4*>(&v[j * 256 + lane * 4]);

    // hoist: issue all 16 row loads first (independent, 1 KiB each per wave)
    float4 ev[4][4];
#pragma unroll
    for (int r = 0; r < 4; ++r) {
        const float* row = enc + (size_t)(s0 + r) * H;
#pragma unroll
        for (int j = 0; j < 4; ++j)
            ev[r][j] = *reinterpret_cast<const float4*>(&row[j * 256 + lane * 4]);
    }

    float e[4];
#pragma unroll
    for (int r = 0; r < 4; ++r) {
        float acc = ev[r][0].x * vv[0].x + ev[r][0].y * vv[0].y +
                    ev[r][0].z * vv[0].z + ev[r][0].w * vv[0].w;
#pragma unroll
        for (int j = 1; j < 4; ++j) {
            acc += ev[r][j].x * vv[j].x + ev[r][j].y * vv[j].y +
                   ev[r][j].z * vv[j].z + ev[r][j].w * vv[j].w;
        }
        // butterfly: every lane ends with the full row sum
#pragma unroll
        for (int off = 32; off > 0; off >>= 1)
            acc += __shfl_xor(acc, off, 64);
        e[r] = acc;
    }

    if (lane == 0) {
        energies[s0 + 0] = e[0];
        energies[s0 + 1] = e[1];
        energies[s0 + 2] = e[2];
        energies[s0 + 3] = e[3];
    }

    // per-wave online softmax partial
    const float mw = fmaxf(fmaxf(e[0], e[1]), fmaxf(e[2], e[3]));
    const float sw = __expf(e[0] - mw) + __expf(e[1] - mw) +
                     __expf(e[2] - mw) + __expf(e[3] - mw);

    __shared__ float lm[4], ls[4];
    if (lane == 0) { lm[wave] = mw; ls[wave] = sw; }
    __syncthreads();
    if (threadIdx.x == 0) {
        const float m = fmaxf(fmaxf(lm[0], lm[1]), fmaxf(lm[2], lm[3]));
        const float s = ls[0] * __expf(lm[0] - m) + ls[1] * __expf(lm[1] - m) +
                        ls[2] * __expf(lm[2] - m) + ls[3] * __expf(lm[3] - m);
        mpart[blockIdx.x] = m;
        spart[blockIdx.x] = s;
    }
}

// ---------------------------------------------------------------------------
// Stage 3: finalize, parallel. 128 blocks x 256 threads.
// Every block redundantly reduces the 2048 (m,s) partials (16 KB, cache-
// resident) then writes its own 256 outputs.
// ---------------------------------------------------------------------------
__global__ void finalize_kernel(const float* __restrict__ energies,
                                const float* __restrict__ mpart,
                                const float* __restrict__ spart,
                                float* __restrict__ out) {
    const int t = threadIdx.x;
    const int lane = t & 63;
    const int wave = t >> 6;
    __shared__ float rm[4], rs[4];

    const float4 ma = *reinterpret_cast<const float4*>(&mpart[t * 8]);
    const float4 mb = *reinterpret_cast<const float4*>(&mpart[t * 8 + 4]);
    const float4 sa = *reinterpret_cast<const float4*>(&spart[t * 8]);
    const float4 sb = *reinterpret_cast<const float4*>(&spart[t * 8 + 4]);

    float mt = fmaxf(fmaxf(fmaxf(ma.x, ma.y), fmaxf(ma.z, ma.w)),
                     fmaxf(fmaxf(mb.x, mb.y), fmaxf(mb.z, mb.w)));
#pragma unroll
    for (int off = 32; off > 0; off >>= 1)
        mt = fmaxf(mt, __shfl_xor(mt, off, 64));
    if (lane == 0) rm[wave] = mt;
    __syncthreads();
    const float gm = fmaxf(fmaxf(rm[0], rm[1]), fmaxf(rm[2], rm[3]));

    float st = sa.x * __expf(ma.x - gm) + sa.y * __expf(ma.y - gm) +
               sa.z * __expf(ma.z - gm) + sa.w * __expf(ma.w - gm) +
               sb.x * __expf(mb.x - gm) + sb.y * __expf(mb.y - gm) +
               sb.z * __expf(mb.z - gm) + sb.w * __expf(mb.w - gm);
#pragma unroll
    for (int off = 32; off > 0; off >>= 1)
        st += __shfl_xor(st, off, 64);
    if (lane == 0) rs[wave] = st;
    __syncthreads();
    const float inv = 1.0f / (rs[0] + rs[1] + rs[2] + rs[3]);

    const int i = blockIdx.x * 256 + t;      // 128*256 = 32768 = S
    out[i] = __expf(energies[i] - gm) * inv;
}

// ---------------------------------------------------------------------------
// Launch: 3 dispatches. Kernel boundaries are the barriers
// (grid.sync() measured ~200 us/sync on this chip in round 1).
// ---------------------------------------------------------------------------
extern "C" void kernel_launch(void* const* d_in, const int* in_sizes, int n_in,
                              void* d_out, int out_size, void* d_ws, size_t ws_size,
                              hipStream_t stream) {
    const float* hidden = (const float*)d_in[0];   // [1024]
    const float* enc    = (const float*)d_in[1];   // [32768, 1024]
    const float* W      = (const float*)d_in[2];   // [1024, 1024]
    // d_in[3] = b: (b . hidden) is constant across s -> cancels in softmax.
    float* out = (float*)d_out;                    // [32768]

    float* v        = (float*)d_ws;        // 1024
    float* energies = v + H;               // 32768
    float* mpart    = energies + S;        // 2048
    float* spart    = mpart + 2048;        // 2048

    matvec_v_kernel<<<32, 256, 0, stream>>>(W, hidden, v);
    energies_kernel<<<2048, 256, 0, stream>>>(enc, v, energies, mpart, spart);
    finalize_kernel<<<128, 256, 0, stream>>>(energies, mpart, spart, out);
}

// Round 4
// 206.175 us; speedup vs baseline: 3.6250x; 1.0019x over previous
//
#include <hip/hip_runtime.h>
#include <math.h>

#define H 1024
#define S 32768

// ---------------------------------------------------------------------------
// Stage 1: v[h] = sum_o W[o,h] * hidden[o], one dispatch.
// 64 blocks x 256 threads. Block b owns cols [b*16, b*16+16).
// Thread t: col-group c = t&3 (float4), row class j = t>>2 (64 classes x 16
// rows). Wave instruction reads 16 rows x 64 B full lines (4 lanes/row).
// hidden staged in LDS; float4 tree-reduce over row classes.
// ---------------------------------------------------------------------------
__global__ void matvec_v_kernel(const float* __restrict__ W,
                                const float* __restrict__ hidden,
                                float* __restrict__ v) {
    __shared__ float sh[H];
    __shared__ float4 red[256];
    const int t = threadIdx.x;
    const int b = blockIdx.x;
    const int c = t & 3;        // float4 col-group within the 16-col slice
    const int j = t >> 2;       // row class 0..63

    *reinterpret_cast<float4*>(&sh[t * 4]) =
        *reinterpret_cast<const float4*>(&hidden[t * 4]);
    __syncthreads();

    const int colbase = b * 16 + c * 4;
    float4 acc = make_float4(0.f, 0.f, 0.f, 0.f);
#pragma unroll
    for (int k = 0; k < 16; ++k) {
        const int o = j + 64 * k;
        const float hv = sh[o];
        const float4 w = *reinterpret_cast<const float4*>(&W[(size_t)o * H + colbase]);
        acc.x += hv * w.x; acc.y += hv * w.y;
        acc.z += hv * w.z; acc.w += hv * w.w;
    }
    red[t] = acc;
    __syncthreads();
#pragma unroll
    for (int off = 128; off >= 4; off >>= 1) {
        if (t < off) {
            float4 a = red[t], bb = red[t + off];
            a.x += bb.x; a.y += bb.y; a.z += bb.z; a.w += bb.w;
            red[t] = a;
        }
        __syncthreads();
    }
    if (t < 4)
        *reinterpret_cast<float4*>(&v[b * 16 + t * 4]) = red[t];
}

// ---------------------------------------------------------------------------
// Stage 2: energies + per-block online-softmax partials.
// 2048 blocks x 256 threads; each 16-lane group owns ONE row (16 rows/block).
// Lane gl covers cols seg*64 + gl*4 (float4); v staged in LDS (bank-clean:
// 16 distinct 16B reads x4-group broadcast, 2-way = free).
// Row reduce = 4 shfl_xor within the group; softmax partial = 2 more
// cross-group shfl_xor (vs 24+ full-wave butterflies before).
// ev[8] streaming buffer keeps VGPR ~56 -> 8 waves/SIMD, 256 KiB/CU in flight.
// ---------------------------------------------------------------------------
__global__ void energies_kernel(const float* __restrict__ enc,
                                const float* __restrict__ v,
                                float* __restrict__ energies,
                                float* __restrict__ mpart,
                                float* __restrict__ spart) {
    __shared__ float sv[H];
    __shared__ float lm[4], ls[4];
    const int t = threadIdx.x;
    const int wave = t >> 6;
    const int lane = t & 63;
    const int grp  = lane >> 4;   // row within wave's 4
    const int gl   = lane & 15;   // lane within group

    *reinterpret_cast<float4*>(&sv[t * 4]) =
        *reinterpret_cast<const float4*>(&v[t * 4]);

    const int row = blockIdx.x * 16 + wave * 4 + grp;
    const float* rp = enc + (size_t)row * H + gl * 4;
    __syncthreads();

    float4 ev[8];
    float acc = 0.f;

    // first 8 segments: hoist loads, then FMA against LDS v
#pragma unroll
    for (int s = 0; s < 8; ++s)
        ev[s] = *reinterpret_cast<const float4*>(&rp[s * 64]);
#pragma unroll
    for (int s = 0; s < 8; ++s) {
        const float4 vv = *reinterpret_cast<const float4*>(&sv[s * 64 + gl * 4]);
        acc += ev[s].x * vv.x + ev[s].y * vv.y + ev[s].z * vv.z + ev[s].w * vv.w;
    }
    // second 8 segments
#pragma unroll
    for (int s = 0; s < 8; ++s)
        ev[s] = *reinterpret_cast<const float4*>(&rp[(s + 8) * 64]);
#pragma unroll
    for (int s = 0; s < 8; ++s) {
        const float4 vv = *reinterpret_cast<const float4*>(&sv[(s + 8) * 64 + gl * 4]);
        acc += ev[s].x * vv.x + ev[s].y * vv.y + ev[s].z * vv.z + ev[s].w * vv.w;
    }

    // row sum within 16-lane group (all 16 lanes end with the row sum)
#pragma unroll
    for (int off = 1; off <= 8; off <<= 1)
        acc += __shfl_xor(acc, off, 64);

    // cross-group fused softmax partial: max then sum of exp over the 4 rows
    float mw = acc;
    mw = fmaxf(mw, __shfl_xor(mw, 16, 64));
    mw = fmaxf(mw, __shfl_xor(mw, 32, 64));
    float sw = __expf(acc - mw);
    sw += __shfl_xor(sw, 16, 64);
    sw += __shfl_xor(sw, 32, 64);

    if (gl == 0) energies[row] = acc;          // 4 consecutive rows per wave
    if (lane == 0) { lm[wave] = mw; ls[wave] = sw; }
    __syncthreads();
    if (t == 0) {
        const float m = fmaxf(fmaxf(lm[0], lm[1]), fmaxf(lm[2], lm[3]));
        const float s = ls[0] * __expf(lm[0] - m) + ls[1] * __expf(lm[1] - m) +
                        ls[2] * __expf(lm[2] - m) + ls[3] * __expf(lm[3] - m);
        mpart[blockIdx.x] = m;
        spart[blockIdx.x] = s;
    }
}

// ---------------------------------------------------------------------------
// Stage 3: finalize, parallel. 128 blocks x 256 threads.
// Every block redundantly reduces the 2048 (m,s) partials (16 KB, cache-
// resident) then writes its own 256 outputs.
// ---------------------------------------------------------------------------
__global__ void finalize_kernel(const float* __restrict__ energies,
                                const float* __restrict__ mpart,
                                const float* __restrict__ spart,
                                float* __restrict__ out) {
    const int t = threadIdx.x;
    const int lane = t & 63;
    const int wave = t >> 6;
    __shared__ float rm[4], rs[4];

    const float4 ma = *reinterpret_cast<const float4*>(&mpart[t * 8]);
    const float4 mb = *reinterpret_cast<const float4*>(&mpart[t * 8 + 4]);
    const float4 sa = *reinterpret_cast<const float4*>(&spart[t * 8]);
    const float4 sb = *reinterpret_cast<const float4*>(&spart[t * 8 + 4]);

    float mt = fmaxf(fmaxf(fmaxf(ma.x, ma.y), fmaxf(ma.z, ma.w)),
                     fmaxf(fmaxf(mb.x, mb.y), fmaxf(mb.z, mb.w)));
#pragma unroll
    for (int off = 32; off > 0; off >>= 1)
        mt = fmaxf(mt, __shfl_xor(mt, off, 64));
    if (lane == 0) rm[wave] = mt;
    __syncthreads();
    const float gm = fmaxf(fmaxf(rm[0], rm[1]), fmaxf(rm[2], rm[3]));

    float st = sa.x * __expf(ma.x - gm) + sa.y * __expf(ma.y - gm) +
               sa.z * __expf(ma.z - gm) + sa.w * __expf(ma.w - gm) +
               sb.x * __expf(mb.x - gm) + sb.y * __expf(mb.y - gm) +
               sb.z * __expf(mb.z - gm) + sb.w * __expf(mb.w - gm);
#pragma unroll
    for (int off = 32; off > 0; off >>= 1)
        st += __shfl_xor(st, off, 64);
    if (lane == 0) rs[wave] = st;
    __syncthreads();
    const float inv = 1.0f / (rs[0] + rs[1] + rs[2] + rs[3]);

    const int i = blockIdx.x * 256 + t;      // 128*256 = 32768 = S
    out[i] = __expf(energies[i] - gm) * inv;
}

// ---------------------------------------------------------------------------
// Launch: 3 dispatches; kernel boundaries are the barriers.
// (grid.sync() measured ~200 us/sync on this chip in round 1 — never again.)
// ---------------------------------------------------------------------------
extern "C" void kernel_launch(void* const* d_in, const int* in_sizes, int n_in,
                              void* d_out, int out_size, void* d_ws, size_t ws_size,
                              hipStream_t stream) {
    const float* hidden = (const float*)d_in[0];   // [1024]
    const float* enc    = (const float*)d_in[1];   // [32768, 1024]
    const float* W      = (const float*)d_in[2];   // [1024, 1024]
    // d_in[3] = b: (b . hidden) is constant across s -> cancels in softmax.
    float* out = (float*)d_out;                    // [32768]

    float* v        = (float*)d_ws;        // 1024
    float* energies = v + H;               // 32768
    float* mpart    = energies + S;        // 2048
    float* spart    = mpart + 2048;        // 2048

    matvec_v_kernel<<<64, 256, 0, stream>>>(W, hidden, v);
    energies_kernel<<<2048, 256, 0, stream>>>(enc, v, energies, mpart, spart);
    finalize_kernel<<<128, 256, 0, stream>>>(energies, mpart, spart, out);
}

// Round 6
// 199.409 us; speedup vs baseline: 3.7480x; 1.0339x over previous
//
#include <hip/hip_runtime.h>
#include <math.h>

#define H 1024
#define S 32768

typedef float f32x4 __attribute__((ext_vector_type(4)));

// ---------------------------------------------------------------------------
// Stage 1: v[h] = sum_o W[o,h] * hidden[o], one dispatch.
// 64 blocks x 256 threads. Block b owns cols [b*16, b*16+16).
// W read via NONTEMPORAL loads: streamed once, do not allocate in L2/IF ->
// avoids evicting dirty poison-fill lines (their writeback would contend
// with our reads inside the timed window).
// ---------------------------------------------------------------------------
__global__ void matvec_v_kernel(const float* __restrict__ W,
                                const float* __restrict__ hidden,
                                float* __restrict__ v) {
    __shared__ float sh[H];
    __shared__ float4 red[256];
    const int t = threadIdx.x;
    const int b = blockIdx.x;
    const int c = t & 3;        // float4 col-group within the 16-col slice
    const int j = t >> 2;       // row class 0..63

    *reinterpret_cast<float4*>(&sh[t * 4]) =
        *reinterpret_cast<const float4*>(&hidden[t * 4]);
    __syncthreads();

    const int colbase = b * 16 + c * 4;
    float4 acc = make_float4(0.f, 0.f, 0.f, 0.f);
#pragma unroll
    for (int k = 0; k < 16; ++k) {
        const int o = j + 64 * k;
        const float hv = sh[o];
        const f32x4 w = __builtin_nontemporal_load(
            reinterpret_cast<const f32x4*>(&W[(size_t)o * H + colbase]));
        acc.x += hv * w.x; acc.y += hv * w.y;
        acc.z += hv * w.z; acc.w += hv * w.w;
    }
    red[t] = acc;
    __syncthreads();
#pragma unroll
    for (int off = 128; off >= 4; off >>= 1) {
        if (t < off) {
            float4 a = red[t], bb = red[t + off];
            a.x += bb.x; a.y += bb.y; a.z += bb.z; a.w += bb.w;
            red[t] = a;
        }
        __syncthreads();
    }
    if (t < 4)
        *reinterpret_cast<float4*>(&v[b * 16 + t * 4]) = red[t];
}

// ---------------------------------------------------------------------------
// Stage 2: energies + per-block online-softmax partials.
// 2048 blocks x 256 threads; each 16-lane group owns ONE row (16 rows/block).
// Structure identical to round-4 (proven) EXCEPT enc loads are NONTEMPORAL:
// enc is read exactly once per iteration; nt read-misses do not allocate in
// IF, so they do not force eviction-writebacks of the 512 MiB poison fill's
// dirty lines during our window. IF hits (the ~half of enc still resident)
// are unaffected.
// ---------------------------------------------------------------------------
__global__ void energies_kernel(const float* __restrict__ enc,
                                const float* __restrict__ v,
                                float* __restrict__ energies,
                                float* __restrict__ mpart,
                                float* __restrict__ spart) {
    __shared__ float sv[H];
    __shared__ float lm[4], ls[4];
    const int t = threadIdx.x;
    const int wave = t >> 6;
    const int lane = t & 63;
    const int grp  = lane >> 4;   // row within wave's 4
    const int gl   = lane & 15;   // lane within group

    *reinterpret_cast<float4*>(&sv[t * 4]) =
        *reinterpret_cast<const float4*>(&v[t * 4]);

    const int row = blockIdx.x * 16 + wave * 4 + grp;
    const f32x4* rp = reinterpret_cast<const f32x4*>(
        enc + (size_t)row * H + gl * 4);   // stride between segments: 16 f32x4
    __syncthreads();

    f32x4 ev[8];
    float acc = 0.f;

    // first 8 segments: hoist nt loads, then FMA against LDS v
#pragma unroll
    for (int s = 0; s < 8; ++s)
        ev[s] = __builtin_nontemporal_load(rp + s * 16);
#pragma unroll
    for (int s = 0; s < 8; ++s) {
        const float4 vv = *reinterpret_cast<const float4*>(&sv[s * 64 + gl * 4]);
        acc += ev[s].x * vv.x + ev[s].y * vv.y + ev[s].z * vv.z + ev[s].w * vv.w;
    }
    // second 8 segments
#pragma unroll
    for (int s = 0; s < 8; ++s)
        ev[s] = __builtin_nontemporal_load(rp + (s + 8) * 16);
#pragma unroll
    for (int s = 0; s < 8; ++s) {
        const float4 vv = *reinterpret_cast<const float4*>(&sv[(s + 8) * 64 + gl * 4]);
        acc += ev[s].x * vv.x + ev[s].y * vv.y + ev[s].z * vv.z + ev[s].w * vv.w;
    }

    // row sum within 16-lane group (all 16 lanes end with the row sum)
#pragma unroll
    for (int off = 1; off <= 8; off <<= 1)
        acc += __shfl_xor(acc, off, 64);

    // cross-group fused softmax partial: max then sum of exp over the 4 rows
    float mw = acc;
    mw = fmaxf(mw, __shfl_xor(mw, 16, 64));
    mw = fmaxf(mw, __shfl_xor(mw, 32, 64));
    float sw = __expf(acc - mw);
    sw += __shfl_xor(sw, 16, 64);
    sw += __shfl_xor(sw, 32, 64);

    if (gl == 0) energies[row] = acc;          // 4 consecutive rows per wave
    if (lane == 0) { lm[wave] = mw; ls[wave] = sw; }
    __syncthreads();
    if (t == 0) {
        const float m = fmaxf(fmaxf(lm[0], lm[1]), fmaxf(lm[2], lm[3]));
        const float s = ls[0] * __expf(lm[0] - m) + ls[1] * __expf(lm[1] - m) +
                        ls[2] * __expf(lm[2] - m) + ls[3] * __expf(lm[3] - m);
        mpart[blockIdx.x] = m;
        spart[blockIdx.x] = s;
    }
}

// ---------------------------------------------------------------------------
// Stage 3: finalize, parallel. 128 blocks x 256 threads.
// Every block redundantly reduces the 2048 (m,s) partials (16 KB, cache-
// resident) then writes its own 256 outputs. energies[] reads stay normal
// (freshly written -> L2/IF hits; nt would forfeit them).
// ---------------------------------------------------------------------------
__global__ void finalize_kernel(const float* __restrict__ energies,
                                const float* __restrict__ mpart,
                                const float* __restrict__ spart,
                                float* __restrict__ out) {
    const int t = threadIdx.x;
    const int lane = t & 63;
    const int wave = t >> 6;
    __shared__ float rm[4], rs[4];

    const float4 ma = *reinterpret_cast<const float4*>(&mpart[t * 8]);
    const float4 mb = *reinterpret_cast<const float4*>(&mpart[t * 8 + 4]);
    const float4 sa = *reinterpret_cast<const float4*>(&spart[t * 8]);
    const float4 sb = *reinterpret_cast<const float4*>(&spart[t * 8 + 4]);

    float mt = fmaxf(fmaxf(fmaxf(ma.x, ma.y), fmaxf(ma.z, ma.w)),
                     fmaxf(fmaxf(mb.x, mb.y), fmaxf(mb.z, mb.w)));
#pragma unroll
    for (int off = 32; off > 0; off >>= 1)
        mt = fmaxf(mt, __shfl_xor(mt, off, 64));
    if (lane == 0) rm[wave] = mt;
    __syncthreads();
    const float gm = fmaxf(fmaxf(rm[0], rm[1]), fmaxf(rm[2], rm[3]));

    float st = sa.x * __expf(ma.x - gm) + sa.y * __expf(ma.y - gm) +
               sa.z * __expf(ma.z - gm) + sa.w * __expf(ma.w - gm) +
               sb.x * __expf(mb.x - gm) + sb.y * __expf(mb.y - gm) +
               sb.z * __expf(mb.z - gm) + sb.w * __expf(mb.w - gm);
#pragma unroll
    for (int off = 32; off > 0; off >>= 1)
        st += __shfl_xor(st, off, 64);
    if (lane == 0) rs[wave] = st;
    __syncthreads();
    const float inv = 1.0f / (rs[0] + rs[1] + rs[2] + rs[3]);

    const int i = blockIdx.x * 256 + t;      // 128*256 = 32768 = S
    out[i] = __expf(energies[i] - gm) * inv;
}

// ---------------------------------------------------------------------------
// Launch: 3 dispatches; kernel boundaries are the barriers.
// grid.sync() ~187 us/sync measured (round 1) = per-block device-scope
// wbL2/invL2 storms — all in-kernel cross-XCD sync designs are closed.
// ---------------------------------------------------------------------------
extern "C" void kernel_launch(void* const* d_in, const int* in_sizes, int n_in,
                              void* d_out, int out_size, void* d_ws, size_t ws_size,
                              hipStream_t stream) {
    const float* hidden = (const float*)d_in[0];   // [1024]
    const float* enc    = (const float*)d_in[1];   // [32768, 1024]
    const float* W      = (const float*)d_in[2];   // [1024, 1024]
    // d_in[3] = b: (b . hidden) is constant across s -> cancels in softmax.
    float* out = (float*)d_out;                    // [32768]

    float* v        = (float*)d_ws;        // 1024
    float* energies = v + H;               // 32768
    float* mpart    = energies + S;        // 2048
    float* spart    = mpart + 2048;        // 2048

    matvec_v_kernel<<<64, 256, 0, stream>>>(W, hidden, v);
    energies_kernel<<<2048, 256, 0, stream>>>(enc, v, energies, mpart, spart);
    finalize_kernel<<<128, 256, 0, stream>>>(energies, mpart, spart, out);
}